// Round 8
// baseline (276.844 us; speedup 1.0000x reference)
//
#include <hip/hip_runtime.h>
#include <math.h>

#define NN 10000
#define NE 160000
#define CAP 128     // bucket capacity; P(in-deg >= 128 | Poisson(16)) ~ 1e-60
#define NT 256
#define WC1_TOTAL (782 * 48)
#define WC5_TOTAL (128 * 60)
#define L1_SPLITS 6
#define L1_KCHUNK 132      // even; 6*132 >= 782
#define L1_NTR 157         // ceil(10000/64) row-tiles of 64
#define L1_TILES (L1_NTR * L1_SPLITS)  // 942
#define CNT_BLKS 625   // 625*256 == NE exactly

struct MegaParams {
  const float* x;
  const int* src;
  const int* dst;
  const float* W1; const float* b1;
  const float* W2; const float* b2;
  const float* W3; const float* b3;
  const float* W4; const float* b4;
  const float* W5; const float* b5;
  int* deg; int* cnt; int* bsrc;
  float* dinv; float* wc1; float* wc5;
  float* ABC1; float* E1; float* B2; float* B3; float* B4;
  float* H4; float* ABC5; float* E5; float* P;
  float* out;
};

// ---- weight concat: Wc [Fin][3*Fp]: [W0-W2 | W1 | W2], pad cols zero ----
__device__ __forceinline__ void wcat_one(const float* __restrict__ W,
                                         float* __restrict__ Wc,
                                         int i, int Fin, int F, int Fp) {
  int w3 = 3 * Fp;
  int row = i / w3;
  int c = i - row * w3;
  int sec = c / Fp;
  int f = c - sec * Fp;
  float v = 0.0f;
  if (f < F) {
    if (sec == 0)      v = W[row * F + f] - W[2 * Fin * F + row * F + f];
    else if (sec == 1) v = W[Fin * F + row * F + f];
    else               v = W[2 * Fin * F + row * F + f];
  }
  Wc[i] = v;
}

// ---- GEMM helpers ----
struct Row8 { float4 lo, hi; };

template <bool AL16>
__device__ __forceinline__ Row8 ld_row8(const float* __restrict__ X, int ldx,
                                        int gr, int M, int kc, int kend) {
  Row8 r;
  r.lo = make_float4(0.f, 0.f, 0.f, 0.f);
  r.hi = make_float4(0.f, 0.f, 0.f, 0.f);
  if (gr < M && kc < kend) {
    const float* xp = X + (size_t)gr * ldx + kc;
    if (kc + 8 <= kend) {
      if (AL16) {
        r.lo = ((const float4*)xp)[0];
        r.hi = ((const float4*)xp)[1];
      } else {  // rows 8B-aligned only
        float2 a = *(const float2*)xp;
        float2 b = *(const float2*)(xp + 2);
        float2 c = *(const float2*)(xp + 4);
        float2 d = *(const float2*)(xp + 6);
        r.lo = make_float4(a.x, a.y, b.x, b.y);
        r.hi = make_float4(c.x, c.y, d.x, d.y);
      }
    } else {
      int rem = kend - kc;  // 1..7
      r.lo.x = xp[0];
      if (rem > 1) r.lo.y = xp[1];
      if (rem > 2) r.lo.z = xp[2];
      if (rem > 3) r.lo.w = xp[3];
      if (rem > 4) r.hi.x = xp[4];
      if (rem > 5) r.hi.y = xp[5];
      if (rem > 6) r.hi.z = xp[6];
    }
  }
  return r;
}

__device__ __forceinline__ float comp8(const Row8& r, int k) {  // k compile-time
  switch (k) {
    case 0: return r.lo.x; case 1: return r.lo.y;
    case 2: return r.lo.z; case 3: return r.lo.w;
    case 4: return r.hi.x; case 5: return r.hi.y;
    case 6: return r.hi.z; default: return r.hi.w;
  }
}

__device__ __forceinline__ float comp4(const float4& v, int k) {  // k compile-time
  switch (k) {
    case 0: return v.x; case 1: return v.y; case 2: return v.z; default: return v.w;
  }
}

// readlane broadcast: reg value from lane i -> scalar operand (no LDS).
__device__ __forceinline__ float rlane(float v, int i) {
  return __int_as_float(__builtin_amdgcn_readlane(__float_as_int(v), i));
}

// Per-8k W window: lane (lk=lane>>4, lc=lane&15) holds W[kb+lk][col0+lc] and
// W[kb+4+lk][col0+lc] (lc<12). Invalid lanes hold 0. (R3-verified mapping.)
__device__ __forceinline__ float2 ldw8(const float* __restrict__ Wf, int kb,
                                       int col0, int lc, int lk) {
  float2 w = make_float2(0.f, 0.f);
  if (lc < 12) {
    int k1 = kb + lk, k2 = kb + 4 + lk;
    if (k1 < 782) w.x = Wf[k1 * 48 + col0 + lc];
    if (k2 < 782) w.y = Wf[k2 * 48 + col0 + lc];
  }
  return w;
}

// ---- L1 GEMM v5: COALESCED X via LDS staging --------------------------------
// R0-R7 lesson: five L1-GEMM variants (LDS-W x2, RT4, readlane, verbatim) all
// land 46-57us; the shared property was per-thread-row X reads (64 scattered
// cache lines per wave-load). v5 stages X[64 rows][32 k] coalesced into
// xs[64][36] (pad 36: b128-aligned, bank-start 4*lane mod 32 conflict-free),
// then each lane ds_read_b128's its own row. W via readlane (zero LDS).
// Block = 64 rows x 48 cols; wave w owns cols [12w,12w+12). K-split 6x132.
__device__ void gemm1_coal(const float* __restrict__ Xg,
                           const float* __restrict__ Wf,
                           float* __restrict__ P,
                           int tile, float (*xs)[36]) {
  int tz = tile / L1_NTR;
  int tr = tile - tz * L1_NTR;
  int row0 = tr * 64;
  int k0 = tz * L1_KCHUNK;
  int kend = k0 + L1_KCHUNK;
  if (kend > 782) kend = 782;
  int wid = threadIdx.x >> 6, lane = threadIdx.x & 63;
  int col0 = wid * 12;
  int lc = lane & 15, lk = lane >> 4;
  int row = row0 + lane;
  float acc[12];
#pragma unroll
  for (int c = 0; c < 12; c++) acc[c] = 0.f;
  for (int kc = k0; kc < kend; kc += 32) {
    __syncthreads();  // WAR: protect xs from previous chunk's readers
    // stage 64 rows x 32 k, coalesced (16 consecutive threads = one row seg)
    for (int i = threadIdx.x; i < 1024; i += NT) {
      int r = i >> 4;
      int c2 = i & 15;
      int ca = kc + 2 * c2;
      float2 v = make_float2(0.f, 0.f);
      if (row0 + r < NN && ca < kend)
        v = *(const float2*)(Xg + (size_t)(row0 + r) * 782 + ca);
      *(float2*)&xs[r][2 * c2] = v;
    }
    // W windows (global, 9.4 KB table, cache-hot) — independent of xs
    float2 w0 = ldw8(Wf, kc, col0, lc, lk);
    float2 w1 = ldw8(Wf, kc + 8, col0, lc, lk);
    float2 w2 = ldw8(Wf, kc + 16, col0, lc, lk);
    float2 w3 = ldw8(Wf, kc + 24, col0, lc, lk);
    __syncthreads();
    float4 xv[8];
#pragma unroll
    for (int q = 0; q < 8; q++) xv[q] = *(const float4*)&xs[lane][4 * q];
#pragma unroll
    for (int j = 0; j < 4; j++) {
      float2 ww = (j == 0) ? w0 : (j == 1) ? w1 : (j == 2) ? w2 : w3;
#pragma unroll
      for (int kin = 0; kin < 8; kin++) {
        float x = comp4(xv[j * 2 + (kin >> 2)], kin & 3);  // static idx
        float wsrc = (kin < 4) ? ww.x : ww.y;
#pragma unroll
        for (int c = 0; c < 12; c++)
          acc[c] = fmaf(x, rlane(wsrc, (kin & 3) * 16 + c), acc[c]);
      }
    }
  }
  if (row < NN) {
    float* pr = P + ((size_t)tz * NN + row) * 48 + col0;
    *(float4*)(pr + 0) = make_float4(acc[0], acc[1], acc[2], acc[3]);
    *(float4*)(pr + 4) = make_float4(acc[4], acc[5], acc[6], acc[7]);
    *(float4*)(pr + 8) = make_float4(acc[8], acc[9], acc[10], acc[11]);
  }
}

// tiles over (row-tile 256) x (col-tile TN) x (k-split). VERBATIM R0 body
// (R5 lesson: re-parameterization costs +8 VGPR/+10us). Used by k_gemm20.
template <int TN, bool AL16, bool DIRECT>
__device__ void gemm_stage(const float* __restrict__ X, int ldx,
                           const float* __restrict__ W, int ldw,
                           float* __restrict__ Y, int ldy,
                           const float* __restrict__ bias, int relu,
                           int M, int Kd, int Nd, int kchunk, int nk,
                           int tile0, int tstride, float* Ws) {
  int ntR = (M + NT - 1) / NT;
  int ntC = Nd / TN;  // exact for all uses
  int ntRC = ntR * ntC;
  int ntiles = ntRC * nk;
  constexpr int W4 = TN / 4;
  for (int tile = tile0; tile < ntiles; tile += tstride) {
    int tz = tile / ntRC;
    int rm = tile - tz * ntRC;
    int tc = rm / ntR;
    int tr = rm - tc * ntR;
    int row0 = tr * NT;
    int col0 = tc * TN;
    int k0 = tz * kchunk;
    int kend = k0 + kchunk;
    if (kend > Kd) kend = Kd;
    int k8 = ((kend - k0) + 7) & ~7;
    __syncthreads();  // protect Ws from previous tile's readers
    for (int idx = threadIdx.x; idx < k8 * W4; idx += NT) {
      int wk = idx / W4;
      int wc = (idx - wk * W4) * 4;
      float4 wv = make_float4(0.f, 0.f, 0.f, 0.f);
      if (k0 + wk < kend)
        wv = *(const float4*)(W + (size_t)(k0 + wk) * ldw + col0 + wc);
      *(float4*)(Ws + wk * TN + wc) = wv;
    }
    __syncthreads();
    float acc[TN];
#pragma unroll
    for (int c = 0; c < TN; c++) acc[c] = 0.f;
    int r = row0 + threadIdx.x;
    int nch = k8 >> 3;
    Row8 cur = ld_row8<AL16>(X, ldx, r, M, k0, kend);
    for (int ci = 0; ci < nch; ci++) {
      Row8 nxt = cur;
      if (ci + 1 < nch) nxt = ld_row8<AL16>(X, ldx, r, M, k0 + (ci + 1) * 8, kend);
      int kb = ci << 3;
#pragma unroll
      for (int k = 0; k < 8; k++) {
        float x0 = comp8(cur, k);
        const float* wr = Ws + (kb + k) * TN;
#pragma unroll
        for (int c = 0; c < TN; c += 4) {
          float4 wv = *(const float4*)(wr + c);  // wave-uniform -> LDS broadcast
          acc[c + 0] += x0 * wv.x; acc[c + 1] += x0 * wv.y;
          acc[c + 2] += x0 * wv.z; acc[c + 3] += x0 * wv.w;
        }
      }
      cur = nxt;
    }
    if (r < M) {
      if (DIRECT) {
        float* yr = Y + (size_t)r * ldy + col0;
#pragma unroll
        for (int c = 0; c < TN; c += 4) {
          float4 v;
          v.x = acc[c + 0] + (bias ? bias[col0 + c + 0] : 0.f);
          v.y = acc[c + 1] + (bias ? bias[col0 + c + 1] : 0.f);
          v.z = acc[c + 2] + (bias ? bias[col0 + c + 2] : 0.f);
          v.w = acc[c + 3] + (bias ? bias[col0 + c + 3] : 0.f);
          if (relu) {
            v.x = fmaxf(v.x, 0.f); v.y = fmaxf(v.y, 0.f);
            v.z = fmaxf(v.z, 0.f); v.w = fmaxf(v.w, 0.f);
          }
          *(float4*)(yr + c) = v;
        }
      } else {
        float* pr = Y + ((size_t)tz * M + r) * Nd + col0;
#pragma unroll
        for (int c = 0; c < TN; c += 4)
          *(float4*)(pr + c) = make_float4(acc[c], acc[c + 1], acc[c + 2], acc[c + 3]);
      }
    }
  }
}

// ---- SpMM stage: wave-per-node grid-stride; S = sum dinv[src]*x;
//      u = -alpha*dinv[node]*S + beta*add + bias (+relu | softmax). ----
__device__ void spmm_stage(const int* __restrict__ cnt,
                           const int* __restrict__ bsrc,
                           const float* __restrict__ dinv,
                           const float* __restrict__ X, int ldx,
                           float* __restrict__ Y, int ldy,
                           const float* __restrict__ add, int lda,
                           const float* __restrict__ bias,
                           float alpha, float beta,
                           int C_log2, int Fstore, int relu, int do_softmax) {
  int wv = threadIdx.x >> 6;
  int lane = threadIdx.x & 63;
  int C = 1 << C_log2;
  int chunk = lane & (C - 1);
  int eslot = lane >> C_log2;
  int Epar = 64 >> C_log2;
  for (int node = blockIdx.x * 4 + wv; node < NN; node += gridDim.x * 4) {
    int cn = cnt[node]; if (cn > CAP) cn = CAP;
    float dn = dinv[node];
    int j0 = node << 7;
    int j1 = j0 + cn;
    float sx = 0.f, sy = 0.f, sz = 0.f, sw = 0.f;
    for (int j = j0 + eslot; j < j1; j += Epar) {
      int sn = bsrc[j];
      float w = dinv[sn];  // 40 KB table, cache-hot
      float4 xv = *(const float4*)(X + (size_t)sn * ldx + (chunk << 2));
      sx += w * xv.x; sy += w * xv.y; sz += w * xv.z; sw += w * xv.w;
    }
    for (int st = C; st < 64; st <<= 1) {
      sx += __shfl_xor(sx, st);
      sy += __shfl_xor(sy, st);
      sz += __shfl_xor(sz, st);
      sw += __shfl_xor(sw, st);
    }
    if (eslot == 0) {
      float am = -alpha * dn;
      int f0 = chunk << 2;
      float4 u = make_float4(am * sx, am * sy, am * sz, am * sw);
      if (add) {
        float4 av = *(const float4*)(add + (size_t)node * lda + f0);
        u.x += beta * av.x; u.y += beta * av.y; u.z += beta * av.z; u.w += beta * av.w;
      }
      if (bias) {
        if (f0 + 0 < Fstore) u.x += bias[f0 + 0];
        if (f0 + 1 < Fstore) u.y += bias[f0 + 1];
        if (f0 + 2 < Fstore) u.z += bias[f0 + 2];
        if (f0 + 3 < Fstore) u.w += bias[f0 + 3];
      }
      if (!do_softmax) {
        if (relu) {
          u.x = fmaxf(u.x, 0.f); u.y = fmaxf(u.y, 0.f);
          u.z = fmaxf(u.z, 0.f); u.w = fmaxf(u.w, 0.f);
        }
        if (f0 + 4 <= Fstore) {
          *(float4*)(Y + (size_t)node * ldy + f0) = u;
        } else {
          float vv[4] = {u.x, u.y, u.z, u.w};
#pragma unroll
          for (int c = 0; c < 4; c++)
            if (f0 + c < Fstore) Y[(size_t)node * ldy + f0 + c] = vv[c];
        }
      } else {
        float v[4] = {u.x, u.y, u.z, u.w};
        float mx = -INFINITY;
#pragma unroll
        for (int c = 0; c < 4; c++)
          if (f0 + c < Fstore) mx = fmaxf(mx, v[c]);
        mx = fmaxf(mx, __shfl_xor(mx, 1));
        mx = fmaxf(mx, __shfl_xor(mx, 2));
        mx = fmaxf(mx, __shfl_xor(mx, 4));
        float e[4];
        float s = 0.f;
#pragma unroll
        for (int c = 0; c < 4; c++) {
          e[c] = (f0 + c < Fstore) ? __expf(v[c] - mx) : 0.f;
          s += e[c];
        }
        s += __shfl_xor(s, 1);
        s += __shfl_xor(s, 2);
        s += __shfl_xor(s, 4);
        float inv = 1.f / s;
#pragma unroll
        for (int c = 0; c < 4; c++) {
          int f = f0 + c;
          if (f < Fstore) Y[(size_t)node * ldy + f] = e[c] * inv;
        }
      }
    }
  }
}

// ---- FUSED T2-spmm + row-GEMM (+bias+relu), layers 2/3 -------------------
template <int F, int C_log2, int LD, int KK, int FOUT, int LDO>
__global__ __launch_bounds__(NT) void k_fused_t2gemm(
    const int* __restrict__ cnt, const int* __restrict__ bsrc,
    const float* __restrict__ dinv, const float* __restrict__ B,
    const float* __restrict__ W, const float* __restrict__ bias,
    float* __restrict__ Y) {
  int wv = threadIdx.x >> 6;
  int lane = threadIdx.x & 63;
  constexpr int C = 1 << C_log2;
  int chunk = lane & (C - 1);
  int eslot = lane >> C_log2;
  constexpr int Epar = 64 >> C_log2;
  int col = lane % FOUT;  // FOUT=32: halves duplicate; FOUT=64: all lanes
  float wr[KK];
#pragma unroll
  for (int k = 0; k < KK; k++) wr[k] = W[k * FOUT + col];
  float bb = bias[col];
  for (int node = blockIdx.x * 4 + wv; node < NN; node += gridDim.x * 4) {
    int cn = cnt[node]; if (cn > CAP) cn = CAP;
    float dn = dinv[node];
    int j0 = node << 7, j1 = j0 + cn;
    float sx = 0.f, sy = 0.f, sz = 0.f, sw = 0.f;
    for (int j = j0 + eslot; j < j1; j += Epar) {
      int sn = bsrc[j];
      float w = dinv[sn];
      float4 xv = *(const float4*)(B + (size_t)sn * LD + F + (chunk << 2));
      sx += w * xv.x; sy += w * xv.y; sz += w * xv.z; sw += w * xv.w;
    }
#pragma unroll
    for (int st = C; st < 64; st <<= 1) {  // full butterfly: ALL lanes get S
      sx += __shfl_xor(sx, st);
      sy += __shfl_xor(sy, st);
      sz += __shfl_xor(sz, st);
      sw += __shfl_xor(sw, st);
    }
    int ridx = (lane < 2 * F) ? lane : (lane - 2 * F);
    float rv0 = B[(size_t)node * LD + ridx];  // l>=2F lanes hold H[l-2F]
    int f = (KK == 48) ? (lane - 2 * F) : lane;
    int cc = (f >> 2) & (C - 1);
    float a0 = __shfl(sx, cc), a1 = __shfl(sy, cc);
    float a2 = __shfl(sz, cc), a3 = __shfl(sw, cc);
    int comp = f & 3;
    float Ssel = (comp == 0) ? a0 : (comp == 1) ? a1 : (comp == 2) ? a2 : a3;
    float t2v = fmaf(-2.f * dn, Ssel, -rv0);
    float acc = bb;
    if (KK == 48) {
      float rv = (lane < 2 * F) ? rv0 : t2v;
#pragma unroll
      for (int k = 0; k < 48; k++) acc = fmaf(rlane(rv, k), wr[k], acc);
    } else {
#pragma unroll
      for (int k = 0; k < 64; k++) acc = fmaf(rlane(rv0, k), wr[k], acc);
#pragma unroll
      for (int k = 64; k < 96; k++) acc = fmaf(rlane(t2v, k - 64), wr[k], acc);
    }
    acc = fmaxf(acc, 0.f);
    if (lane < FOUT) Y[(size_t)node * LDO + col] = acc;
  }
}

// ---- FUSED layer-4 T2-spmm + [H3|T1|T2] @ W4(192x128) + b4, relu — v2 ----
__global__ __launch_bounds__(NT) void k_fused_t2gemm4(
    const int* __restrict__ cnt, const int* __restrict__ bsrc,
    const float* __restrict__ dinv, const float* __restrict__ B,
    const float* __restrict__ W, const float* __restrict__ bias,
    float* __restrict__ Y) {
  __shared__ float t2s[64];
  __shared__ float pacc[128];
  int t = threadIdx.x;
  int wid = t >> 6;
  int lane = t & 63;
  int col = t & 127;
  int kh = t >> 7;
  int chunk = lane & 3;   // 4-float chunk within this wave's 16 features
  int eslot = lane >> 2;  // 16 edges in parallel
  float wr[96];
#pragma unroll
  for (int k = 0; k < 96; k++) wr[k] = W[(96 * kh + k) * 128 + col];
  float bb = bias[col];
  int foff = 64 + wid * 16 + (chunk << 2);  // T1 features [16*wid, 16*wid+16)
  for (int node = blockIdx.x; node < NN; node += gridDim.x) {
    int cn = cnt[node]; if (cn > CAP) cn = CAP;
    float dn = dinv[node];
    int j0 = node << 7, j1 = j0 + cn;
    float sx = 0.f, sy = 0.f, sz = 0.f, sw = 0.f;
    for (int j = j0 + eslot; j < j1; j += 16) {
      int sn = bsrc[j];
      float w = dinv[sn];
      float4 xv = *(const float4*)(B + (size_t)sn * 192 + foff);
      sx += w * xv.x; sy += w * xv.y; sz += w * xv.z; sw += w * xv.w;
    }
#pragma unroll
    for (int st = 4; st < 64; st <<= 1) {
      sx += __shfl_xor(sx, st);
      sy += __shfl_xor(sy, st);
      sz += __shfl_xor(sz, st);
      sw += __shfl_xor(sw, st);
    }
    if (eslot == 0) {  // lanes 0..3 write this wave's 16 raw -2*dn*S values
      float m = -2.f * dn;
      int o = wid * 16 + (chunk << 2);
      t2s[o + 0] = m * sx;
      t2s[o + 1] = m * sy;
      t2s[o + 2] = m * sz;
      t2s[o + 3] = m * sw;
    }
    // row loads (independent of t2s; issue before barrier)
    float hA = B[(size_t)node * 192 + lane];        // H3[lane]
    float hB = B[(size_t)node * 192 + 64 + lane];   // T1[lane]
    __syncthreads();
    float acc = 0.f;
    if (kh == 0) {
#pragma unroll
      for (int k = 0; k < 64; k++) acc = fmaf(rlane(hA, k), wr[k], acc);
#pragma unroll
      for (int k = 64; k < 96; k++) acc = fmaf(rlane(hB, k - 64), wr[k], acc);
    } else {
      float t2v = t2s[lane] - hA;  // T2[lane] = -2*dn*S[lane] - H3[lane]
#pragma unroll
      for (int k = 0; k < 32; k++) acc = fmaf(rlane(hB, 32 + k), wr[k], acc);
#pragma unroll
      for (int k = 32; k < 96; k++) acc = fmaf(rlane(t2v, k - 32), wr[k], acc);
      pacc[col] = acc;
    }
    __syncthreads();
    if (kh == 0) {
      float tot = acc + pacc[col] + bb;
      tot = fmaxf(tot, 0.f);
      Y[(size_t)node * 128 + col] = tot;
    }
    __syncthreads();  // WAR: next iteration overwrites t2s/pacc
  }
}

// ---------------- kernels (14-dispatch chain; no cooperative launch) --------
// Learnings: grid.sync ~100us -> plain launches. R0-R7: L1 GEMM stuck at
// 46-57us across 5 W-side variants; shared flaw = scattered per-thread-row X
// reads -> v5 stages X coalesced through LDS. Verbatim-restore discipline for
// everything else (R5 lesson). F2/F3/F4 fusions keep 14 dispatches.

// L0: zero deg/cnt + both weight concats
__global__ __launch_bounds__(NT) void k_zero_wcat(MegaParams p) {
  int tid = blockIdx.x * NT + threadIdx.x;
  int TT = gridDim.x * NT;
  for (int i = tid; i < 2 * NN; i += TT) p.deg[i] = 0;  // deg+cnt contiguous
  for (int i = tid; i < WC1_TOTAL; i += TT) wcat_one(p.W1, p.wc1, i, 782, 16, 16);
  for (int i = tid; i < WC5_TOTAL; i += TT) wcat_one(p.W5, p.wc5, i, 128, 19, 20);
}

// L1: degree count + bucket insert (blocks 0..624) PACKED with
//     L1-GEMM v5 coalesced-X tiles (blocks 625..1566).
__global__ __launch_bounds__(NT) void k_count_gemm1(MegaParams p) {
  __shared__ float xs[64][36];  // 9.2 KB (gemm branch only)
  if (blockIdx.x < CNT_BLKS) {
    int e = blockIdx.x * NT + threadIdx.x;  // 0..159999 exactly
    int s = p.src[e], d = p.dst[e];
    atomicAdd(&p.deg[s], 1);
    int slot = atomicAdd(&p.cnt[d], 1);
    if (slot < CAP) p.bsrc[(d << 7) + slot] = s;
  } else {
    gemm1_coal(p.x, p.wc1, p.P, blockIdx.x - CNT_BLKS, xs);
  }
}

// L2: dinv + reduce ABC1
__global__ __launch_bounds__(NT) void k_reduce_dinv(MegaParams p) {
  int tid = blockIdx.x * NT + threadIdx.x;
  int TT = gridDim.x * NT;
  for (int i = tid; i < NN; i += TT) {
    int d = p.deg[i];
    p.dinv[i] = d > 0 ? 1.0f / sqrtf((float)d) : 0.0f;
  }
  for (int i = tid; i < NN * 48; i += TT) {
    float s = 0.f;
#pragma unroll
    for (int z = 0; z < L1_SPLITS; z++) s += p.P[(size_t)z * (NN * 48) + i];
    p.ABC1[i] = s;
  }
}

// SpMM launcher kernel
__global__ __launch_bounds__(NT) void k_spmm(
    const int* cnt, const int* bsrc, const float* dinv,
    const float* X, int ldx, float* Y, int ldy,
    const float* add, int lda, const float* bias,
    float alpha, float beta, int C_log2, int Fstore, int relu, int do_softmax) {
  spmm_stage(cnt, bsrc, dinv, X, ldx, Y, ldy, add, lda, bias,
             alpha, beta, C_log2, Fstore, relu, do_softmax);
}

// Direct GEMM launcher (full-K, fused bias/relu) — only L14 remains tiled
__global__ __launch_bounds__(NT, 2) void k_gemm20(
    const float* X, int ldx, const float* W, int ldw, float* Y, int ldy,
    const float* bias, int relu, int Kd, int Nd) {
  __shared__ float Ws[128 * 20];
  gemm_stage<20, true, true>(X, ldx, W, ldw, Y, ldy, bias, relu,
                             NN, Kd, Nd, Kd, 1, blockIdx.x, gridDim.x, Ws);
}

// ---------------- host ----------------

extern "C" void kernel_launch(void* const* d_in, const int* in_sizes, int n_in,
                              void* d_out, int out_size, void* d_ws, size_t ws_size,
                              hipStream_t stream) {
  (void)in_sizes; (void)n_in; (void)out_size; (void)ws_size;
  char* p = (char*)d_ws;
  auto alloc = [&](size_t bytes) {
    char* r = p;
    p += (bytes + 255) & ~(size_t)255;
    return r;
  };
  int*   i_deg  = (int*)alloc(sizeof(int) * NN * 2);  // deg, cnt contiguous
  int*   i_bsrc = (int*)alloc(sizeof(int) * NN * CAP);
  float* f_dinv = (float*)alloc(sizeof(float) * NN);
  float* wc1    = (float*)alloc(sizeof(float) * WC1_TOTAL);
  float* wc5    = (float*)alloc(sizeof(float) * WC5_TOTAL);
  float* R1     = (float*)alloc(sizeof(float) * NN * 96);   // ABC1(48)->B3(96)->ABC5(60)
  float* R2     = (float*)alloc(sizeof(float) * NN * 192);  // E1(16)->B4(192)->E5(32)
  float* R3     = (float*)alloc(sizeof(float) * NN * 128);  // B2(48)->H4(128)
  float* P      = (float*)alloc(sizeof(float) * NN * 48 * L1_SPLITS);

  MegaParams mp;
  mp.x   = (const float*)d_in[0];
  const int* ei = (const int*)d_in[1];
  mp.src = ei;
  mp.dst = ei + NE;
  mp.W1 = (const float*)d_in[2];  mp.b1 = (const float*)d_in[3];
  mp.W2 = (const float*)d_in[4];  mp.b2 = (const float*)d_in[5];
  mp.W3 = (const float*)d_in[6];  mp.b3 = (const float*)d_in[7];
  mp.W4 = (const float*)d_in[8];  mp.b4 = (const float*)d_in[9];
  mp.W5 = (const float*)d_in[10]; mp.b5 = (const float*)d_in[11];
  mp.deg = i_deg; mp.cnt = i_deg + NN; mp.bsrc = i_bsrc;
  mp.dinv = f_dinv; mp.wc1 = wc1; mp.wc5 = wc5;
  mp.ABC1 = R1; mp.B3 = R1; mp.ABC5 = R1;
  mp.E1 = R2;   mp.B4 = R2; mp.E5 = R2;
  mp.B2 = R3;   mp.H4 = R3;
  mp.P = P;
  mp.out = (float*)d_out;

  // L0: zero + wcat
  k_zero_wcat<<<160, NT, 0, stream>>>(mp);
  // L1: count (625 blocks) + L1-GEMM v5 coalesced-X (942 tiles)
  k_count_gemm1<<<CNT_BLKS + L1_TILES, NT, 0, stream>>>(mp);
  // L2: dinv + reduce ABC1 (6 partials now)
  k_reduce_dinv<<<(NN * 48 + NT - 1) / NT, NT, 0, stream>>>(mp);
  // L3: E1 = 2*L(C) + B
  k_spmm<<<2500, NT, 0, stream>>>(mp.cnt, mp.bsrc, mp.dinv, mp.ABC1 + 32, 48,
                                  mp.E1, 16, mp.ABC1 + 16, 48, nullptr,
                                  2.f, 1.f, 2, 16, 0, 0);
  // L4: H1 = relu(L(E1) + A + b1) -> B2 slot0 (ld48)
  k_spmm<<<2500, NT, 0, stream>>>(mp.cnt, mp.bsrc, mp.dinv, mp.E1, 16,
                                  mp.B2, 48, mp.ABC1, 48, mp.b1,
                                  1.f, 1.f, 2, 16, 1, 0);
  // L5: layer-2 T1 -> B2+16 (ld48)
  k_spmm<<<2500, NT, 0, stream>>>(mp.cnt, mp.bsrc, mp.dinv, mp.B2, 48,
                                  mp.B2 + 16, 48, nullptr, 0, nullptr,
                                  1.f, 0.f, 2, 16, 0, 0);
  // F2: fused layer-2 T2-spmm + [H|T1|T2]@W2+b2, relu -> B3 slot0 (ld96)
  k_fused_t2gemm<16, 2, 48, 48, 32, 96><<<1250, NT, 0, stream>>>(
      mp.cnt, mp.bsrc, mp.dinv, mp.B2, mp.W2, mp.b2, mp.B3);
  // L8: layer-3 T1 -> B3+32 (ld96)
  k_spmm<<<2500, NT, 0, stream>>>(mp.cnt, mp.bsrc, mp.dinv, mp.B3, 96,
                                  mp.B3 + 32, 96, nullptr, 0, nullptr,
                                  1.f, 0.f, 3, 32, 0, 0);
  // F3: fused layer-3 T2-spmm + [H|T1|T2]@W3+b3, relu -> B4 slot0 (ld192)
  k_fused_t2gemm<32, 3, 96, 96, 64, 192><<<1250, NT, 0, stream>>>(
      mp.cnt, mp.bsrc, mp.dinv, mp.B3, mp.W3, mp.b3, mp.B4);
  // L11: layer-4 T1 -> B4+64 (ld192)
  k_spmm<<<2500, NT, 0, stream>>>(mp.cnt, mp.bsrc, mp.dinv, mp.B4, 192,
                                  mp.B4 + 64, 192, nullptr, 0, nullptr,
                                  1.f, 0.f, 4, 64, 0, 0);
  // F4 v2: fused layer-4 T2-spmm + [H3|T1|T2]@W4+b4, relu -> H4 (ld128)
  k_fused_t2gemm4<<<2500, NT, 0, stream>>>(
      mp.cnt, mp.bsrc, mp.dinv, mp.B4, mp.W4, mp.b4, mp.H4);
  // L14: ABC5 = H4 @ wc5 (ld60)
  k_gemm20<<<120, NT, 0, stream>>>(mp.H4, 128, mp.wc5, 60, mp.ABC5, 60, nullptr, 0,
                                   128, 60);
  // L15: E5 = 2*L(C) + B (Fstore 20; cols >= 20 masked)
  k_spmm<<<2500, NT, 0, stream>>>(mp.cnt, mp.bsrc, mp.dinv, mp.ABC5 + 40, 60,
                                  mp.E5, 32, mp.ABC5 + 20, 60, nullptr,
                                  2.f, 1.f, 3, 20, 0, 0);
  // L16: out = softmax(L(E5) + A + b5) (ld19)
  k_spmm<<<2500, NT, 0, stream>>>(mp.cnt, mp.bsrc, mp.dinv, mp.E5, 32,
                                  mp.out, 19, mp.ABC5, 60, mp.b5,
                                  1.f, 1.f, 3, 19, 0, 1);
}

// Round 9
// 269.746 us; speedup vs baseline: 1.0263x; 1.0263x over previous
//
#include <hip/hip_runtime.h>
#include <math.h>

#define NN 10000
#define NE 160000
#define CAP 128     // bucket capacity; P(in-deg >= 128 | Poisson(16)) ~ 1e-60
#define NT 256
#define WC1_TOTAL (782 * 48)
#define WC5_TOTAL (128 * 60)
#define L1_SPLITS 12
#define L1_KCHUNK 66   // even (float2 path); 12*66 >= 782
#define CNT_BLKS 625   // 625*256 == NE exactly

struct MegaParams {
  const float* x;
  const int* src;
  const int* dst;
  const float* W1; const float* b1;
  const float* W2; const float* b2;
  const float* W3; const float* b3;
  const float* W4; const float* b4;
  const float* W5; const float* b5;
  int* deg; int* cnt; int* bsrc;
  float* dinv; float* wc1; float* wc5;
  float* ABC1; float* E1; float* B2; float* B3; float* B4;
  float* H4; float* ABC5; float* E5; float* P;
  float* out;
};

// ---- weight concat: Wc [Fin][3*Fp]: [W0-W2 | W1 | W2], pad cols zero ----
__device__ __forceinline__ void wcat_one(const float* __restrict__ W,
                                         float* __restrict__ Wc,
                                         int i, int Fin, int F, int Fp) {
  int w3 = 3 * Fp;
  int row = i / w3;
  int c = i - row * w3;
  int sec = c / Fp;
  int f = c - sec * Fp;
  float v = 0.0f;
  if (f < F) {
    if (sec == 0)      v = W[row * F + f] - W[2 * Fin * F + row * F + f];
    else if (sec == 1) v = W[Fin * F + row * F + f];
    else               v = W[2 * Fin * F + row * F + f];
  }
  Wc[i] = v;
}

// ---- GEMM stage (register-X prefetch, LDS-W broadcast, RT=1) ----
// VERBATIM round-0 body (proven 46-48us in the packed L1 dispatch; R5/R8
// lessons: any re-parameterization or X-restaging regresses — six variants
// tried, R0 config is the measured optimum; do not touch).
struct Row8 { float4 lo, hi; };

template <bool AL16>
__device__ __forceinline__ Row8 ld_row8(const float* __restrict__ X, int ldx,
                                        int gr, int M, int kc, int kend) {
  Row8 r;
  r.lo = make_float4(0.f, 0.f, 0.f, 0.f);
  r.hi = make_float4(0.f, 0.f, 0.f, 0.f);
  if (gr < M && kc < kend) {
    const float* xp = X + (size_t)gr * ldx + kc;
    if (kc + 8 <= kend) {
      if (AL16) {
        r.lo = ((const float4*)xp)[0];
        r.hi = ((const float4*)xp)[1];
      } else {  // rows 8B-aligned only (ldx=782, kc even)
        float2 a = *(const float2*)xp;
        float2 b = *(const float2*)(xp + 2);
        float2 c = *(const float2*)(xp + 4);
        float2 d = *(const float2*)(xp + 6);
        r.lo = make_float4(a.x, a.y, b.x, b.y);
        r.hi = make_float4(c.x, c.y, d.x, d.y);
      }
    } else {
      int rem = kend - kc;  // 1..7
      r.lo.x = xp[0];
      if (rem > 1) r.lo.y = xp[1];
      if (rem > 2) r.lo.z = xp[2];
      if (rem > 3) r.lo.w = xp[3];
      if (rem > 4) r.hi.x = xp[4];
      if (rem > 5) r.hi.y = xp[5];
      if (rem > 6) r.hi.z = xp[6];
    }
  }
  return r;
}

__device__ __forceinline__ float comp8(const Row8& r, int k) {  // k compile-time
  switch (k) {
    case 0: return r.lo.x; case 1: return r.lo.y;
    case 2: return r.lo.z; case 3: return r.lo.w;
    case 4: return r.hi.x; case 5: return r.hi.y;
    case 6: return r.hi.z; default: return r.hi.w;
  }
}

// readlane broadcast: reg value from lane i -> scalar operand (no LDS).
__device__ __forceinline__ float rlane(float v, int i) {
  return __int_as_float(__builtin_amdgcn_readlane(__float_as_int(v), i));
}

// tiles over (row-tile 256) x (col-tile TN) x (k-split), iterated from tile0
// by tstride. DIRECT: fused bias/relu to Y(ldy); else partials P[tz][M*Nd].
template <int TN, bool AL16, bool DIRECT>
__device__ void gemm_stage(const float* __restrict__ X, int ldx,
                           const float* __restrict__ W, int ldw,
                           float* __restrict__ Y, int ldy,
                           const float* __restrict__ bias, int relu,
                           int M, int Kd, int Nd, int kchunk, int nk,
                           int tile0, int tstride, float* Ws) {
  int ntR = (M + NT - 1) / NT;
  int ntC = Nd / TN;  // exact for all uses
  int ntRC = ntR * ntC;
  int ntiles = ntRC * nk;
  constexpr int W4 = TN / 4;
  for (int tile = tile0; tile < ntiles; tile += tstride) {
    int tz = tile / ntRC;
    int rm = tile - tz * ntRC;
    int tc = rm / ntR;
    int tr = rm - tc * ntR;
    int row0 = tr * NT;
    int col0 = tc * TN;
    int k0 = tz * kchunk;
    int kend = k0 + kchunk;
    if (kend > Kd) kend = Kd;
    int k8 = ((kend - k0) + 7) & ~7;
    __syncthreads();  // protect Ws from previous tile's readers
    for (int idx = threadIdx.x; idx < k8 * W4; idx += NT) {
      int wk = idx / W4;
      int wc = (idx - wk * W4) * 4;
      float4 wv = make_float4(0.f, 0.f, 0.f, 0.f);
      if (k0 + wk < kend)
        wv = *(const float4*)(W + (size_t)(k0 + wk) * ldw + col0 + wc);
      *(float4*)(Ws + wk * TN + wc) = wv;
    }
    __syncthreads();
    float acc[TN];
#pragma unroll
    for (int c = 0; c < TN; c++) acc[c] = 0.f;
    int r = row0 + threadIdx.x;
    int nch = k8 >> 3;
    Row8 cur = ld_row8<AL16>(X, ldx, r, M, k0, kend);
    for (int ci = 0; ci < nch; ci++) {
      Row8 nxt = cur;
      if (ci + 1 < nch) nxt = ld_row8<AL16>(X, ldx, r, M, k0 + (ci + 1) * 8, kend);
      int kb = ci << 3;
#pragma unroll
      for (int k = 0; k < 8; k++) {
        float x0 = comp8(cur, k);
        const float* wr = Ws + (kb + k) * TN;
#pragma unroll
        for (int c = 0; c < TN; c += 4) {
          float4 wv = *(const float4*)(wr + c);  // wave-uniform -> LDS broadcast
          acc[c + 0] += x0 * wv.x; acc[c + 1] += x0 * wv.y;
          acc[c + 2] += x0 * wv.z; acc[c + 3] += x0 * wv.w;
        }
      }
      cur = nxt;
    }
    if (r < M) {
      if (DIRECT) {
        float* yr = Y + (size_t)r * ldy + col0;
#pragma unroll
        for (int c = 0; c < TN; c += 4) {
          float4 v;
          v.x = acc[c + 0] + (bias ? bias[col0 + c + 0] : 0.f);
          v.y = acc[c + 1] + (bias ? bias[col0 + c + 1] : 0.f);
          v.z = acc[c + 2] + (bias ? bias[col0 + c + 2] : 0.f);
          v.w = acc[c + 3] + (bias ? bias[col0 + c + 3] : 0.f);
          if (relu) {
            v.x = fmaxf(v.x, 0.f); v.y = fmaxf(v.y, 0.f);
            v.z = fmaxf(v.z, 0.f); v.w = fmaxf(v.w, 0.f);
          }
          *(float4*)(yr + c) = v;
        }
      } else {
        float* pr = Y + ((size_t)tz * M + r) * Nd + col0;
#pragma unroll
        for (int c = 0; c < TN; c += 4)
          *(float4*)(pr + c) = make_float4(acc[c], acc[c + 1], acc[c + 2], acc[c + 3]);
      }
    }
  }
}

// ---- SpMM stage: wave-per-node grid-stride; S = sum dinv[src]*x;
//      u = -alpha*dinv[node]*S + beta*add + bias (+relu | softmax). ----
__device__ void spmm_stage(const int* __restrict__ cnt,
                           const int* __restrict__ bsrc,
                           const float* __restrict__ dinv,
                           const float* __restrict__ X, int ldx,
                           float* __restrict__ Y, int ldy,
                           const float* __restrict__ add, int lda,
                           const float* __restrict__ bias,
                           float alpha, float beta,
                           int C_log2, int Fstore, int relu, int do_softmax) {
  int wv = threadIdx.x >> 6;
  int lane = threadIdx.x & 63;
  int C = 1 << C_log2;
  int chunk = lane & (C - 1);
  int eslot = lane >> C_log2;
  int Epar = 64 >> C_log2;
  for (int node = blockIdx.x * 4 + wv; node < NN; node += gridDim.x * 4) {
    int cn = cnt[node]; if (cn > CAP) cn = CAP;
    float dn = dinv[node];
    int j0 = node << 7;
    int j1 = j0 + cn;
    float sx = 0.f, sy = 0.f, sz = 0.f, sw = 0.f;
    for (int j = j0 + eslot; j < j1; j += Epar) {
      int sn = bsrc[j];
      float w = dinv[sn];  // 40 KB table, cache-hot
      float4 xv = *(const float4*)(X + (size_t)sn * ldx + (chunk << 2));
      sx += w * xv.x; sy += w * xv.y; sz += w * xv.z; sw += w * xv.w;
    }
    for (int st = C; st < 64; st <<= 1) {
      sx += __shfl_xor(sx, st);
      sy += __shfl_xor(sy, st);
      sz += __shfl_xor(sz, st);
      sw += __shfl_xor(sw, st);
    }
    if (eslot == 0) {
      float am = -alpha * dn;
      int f0 = chunk << 2;
      float4 u = make_float4(am * sx, am * sy, am * sz, am * sw);
      if (add) {
        float4 av = *(const float4*)(add + (size_t)node * lda + f0);
        u.x += beta * av.x; u.y += beta * av.y; u.z += beta * av.z; u.w += beta * av.w;
      }
      if (bias) {
        if (f0 + 0 < Fstore) u.x += bias[f0 + 0];
        if (f0 + 1 < Fstore) u.y += bias[f0 + 1];
        if (f0 + 2 < Fstore) u.z += bias[f0 + 2];
        if (f0 + 3 < Fstore) u.w += bias[f0 + 3];
      }
      if (!do_softmax) {
        if (relu) {
          u.x = fmaxf(u.x, 0.f); u.y = fmaxf(u.y, 0.f);
          u.z = fmaxf(u.z, 0.f); u.w = fmaxf(u.w, 0.f);
        }
        if (f0 + 4 <= Fstore) {
          *(float4*)(Y + (size_t)node * ldy + f0) = u;
        } else {
          float vv[4] = {u.x, u.y, u.z, u.w};
#pragma unroll
          for (int c = 0; c < 4; c++)
            if (f0 + c < Fstore) Y[(size_t)node * ldy + f0 + c] = vv[c];
        }
      } else {
        float v[4] = {u.x, u.y, u.z, u.w};
        float mx = -INFINITY;
#pragma unroll
        for (int c = 0; c < 4; c++)
          if (f0 + c < Fstore) mx = fmaxf(mx, v[c]);
        mx = fmaxf(mx, __shfl_xor(mx, 1));
        mx = fmaxf(mx, __shfl_xor(mx, 2));
        mx = fmaxf(mx, __shfl_xor(mx, 4));
        float e[4];
        float s = 0.f;
#pragma unroll
        for (int c = 0; c < 4; c++) {
          e[c] = (f0 + c < Fstore) ? __expf(v[c] - mx) : 0.f;
          s += e[c];
        }
        s += __shfl_xor(s, 1);
        s += __shfl_xor(s, 2);
        s += __shfl_xor(s, 4);
        float inv = 1.f / s;
#pragma unroll
        for (int c = 0; c < 4; c++) {
          int f = f0 + c;
          if (f < Fstore) Y[(size_t)node * ldy + f] = e[c] * inv;
        }
      }
    }
  }
}

// ---- FUSED T2-spmm + row-GEMM (+bias+relu), layers 2/3 -------------------
template <int F, int C_log2, int LD, int KK, int FOUT, int LDO>
__global__ __launch_bounds__(NT) void k_fused_t2gemm(
    const int* __restrict__ cnt, const int* __restrict__ bsrc,
    const float* __restrict__ dinv, const float* __restrict__ B,
    const float* __restrict__ W, const float* __restrict__ bias,
    float* __restrict__ Y) {
  int wv = threadIdx.x >> 6;
  int lane = threadIdx.x & 63;
  constexpr int C = 1 << C_log2;
  int chunk = lane & (C - 1);
  int eslot = lane >> C_log2;
  constexpr int Epar = 64 >> C_log2;
  int col = lane % FOUT;  // FOUT=32: halves duplicate; FOUT=64: all lanes
  float wr[KK];
#pragma unroll
  for (int k = 0; k < KK; k++) wr[k] = W[k * FOUT + col];
  float bb = bias[col];
  for (int node = blockIdx.x * 4 + wv; node < NN; node += gridDim.x * 4) {
    int cn = cnt[node]; if (cn > CAP) cn = CAP;
    float dn = dinv[node];
    int j0 = node << 7, j1 = j0 + cn;
    float sx = 0.f, sy = 0.f, sz = 0.f, sw = 0.f;
    for (int j = j0 + eslot; j < j1; j += Epar) {
      int sn = bsrc[j];
      float w = dinv[sn];
      float4 xv = *(const float4*)(B + (size_t)sn * LD + F + (chunk << 2));
      sx += w * xv.x; sy += w * xv.y; sz += w * xv.z; sw += w * xv.w;
    }
#pragma unroll
    for (int st = C; st < 64; st <<= 1) {  // full butterfly: ALL lanes get S
      sx += __shfl_xor(sx, st);
      sy += __shfl_xor(sy, st);
      sz += __shfl_xor(sz, st);
      sw += __shfl_xor(sw, st);
    }
    int ridx = (lane < 2 * F) ? lane : (lane - 2 * F);
    float rv0 = B[(size_t)node * LD + ridx];  // l>=2F lanes hold H[l-2F]
    int f = (KK == 48) ? (lane - 2 * F) : lane;
    int cc = (f >> 2) & (C - 1);
    float a0 = __shfl(sx, cc), a1 = __shfl(sy, cc);
    float a2 = __shfl(sz, cc), a3 = __shfl(sw, cc);
    int comp = f & 3;
    float Ssel = (comp == 0) ? a0 : (comp == 1) ? a1 : (comp == 2) ? a2 : a3;
    float t2v = fmaf(-2.f * dn, Ssel, -rv0);
    float acc = bb;
    if (KK == 48) {
      float rv = (lane < 2 * F) ? rv0 : t2v;
#pragma unroll
      for (int k = 0; k < 48; k++) acc = fmaf(rlane(rv, k), wr[k], acc);
    } else {
#pragma unroll
      for (int k = 0; k < 64; k++) acc = fmaf(rlane(rv0, k), wr[k], acc);
#pragma unroll
      for (int k = 64; k < 96; k++) acc = fmaf(rlane(t2v, k - 64), wr[k], acc);
    }
    acc = fmaxf(acc, 0.f);
    if (lane < FOUT) Y[(size_t)node * LDO + col] = acc;
  }
}

// ---- FUSED layer-4 T2-spmm + [H3|T1|T2]@W4+b4+relu + H4@wc5 — v3 ---------
// v2 (R7-verified) plus the L14 GEMM absorbed into the epilogue: H4[r] never
// hits global (it was consumed only by L14). After ph4[128] is complete,
// a 4-way split-k epilogue (240 threads x 32 FMAs, wc5 staged once per block
// into LDS) produces ABC5[r][0:60] directly. Removes one dispatch + the H4
// store + its reload.
__global__ __launch_bounds__(NT) void k_fused_t2gemm4(
    const int* __restrict__ cnt, const int* __restrict__ bsrc,
    const float* __restrict__ dinv, const float* __restrict__ B,
    const float* __restrict__ W, const float* __restrict__ bias,
    const float* __restrict__ wc5, float* __restrict__ ABC5) {
  __shared__ float t2s[64];
  __shared__ float pacc[128];
  __shared__ float ph4[128];
  __shared__ float pabc[4][60];
  __shared__ float wcs[128 * 60];  // 30.7 KB
  int t = threadIdx.x;
  int wid = t >> 6;
  int lane = t & 63;
  int col = t & 127;
  int kh = t >> 7;
  int chunk = lane & 3;   // 4-float chunk within this wave's 16 features
  int eslot = lane >> 2;  // 16 edges in parallel
  float wr[96];
#pragma unroll
  for (int k = 0; k < 96; k++) wr[k] = W[(96 * kh + k) * 128 + col];
  float bb = bias[col];
  for (int i = t; i < 128 * 60; i += NT) wcs[i] = wc5[i];  // once per block
  int foff = 64 + wid * 16 + (chunk << 2);  // T1 features [16*wid, 16*wid+16)
  int j60 = t % 60;   // epilogue output col
  int kseg = t / 60;  // 0..3 active (t<240)
  for (int node = blockIdx.x; node < NN; node += gridDim.x) {
    int cn = cnt[node]; if (cn > CAP) cn = CAP;
    float dn = dinv[node];
    int j0 = node << 7, j1 = j0 + cn;
    float sx = 0.f, sy = 0.f, sz = 0.f, sw = 0.f;
    for (int j = j0 + eslot; j < j1; j += 16) {
      int sn = bsrc[j];
      float w = dinv[sn];
      float4 xv = *(const float4*)(B + (size_t)sn * 192 + foff);
      sx += w * xv.x; sy += w * xv.y; sz += w * xv.z; sw += w * xv.w;
    }
#pragma unroll
    for (int st = 4; st < 64; st <<= 1) {
      sx += __shfl_xor(sx, st);
      sy += __shfl_xor(sy, st);
      sz += __shfl_xor(sz, st);
      sw += __shfl_xor(sw, st);
    }
    if (eslot == 0) {  // lanes 0..3 write this wave's 16 raw -2*dn*S values
      float m = -2.f * dn;
      int o = wid * 16 + (chunk << 2);
      t2s[o + 0] = m * sx;
      t2s[o + 1] = m * sy;
      t2s[o + 2] = m * sz;
      t2s[o + 3] = m * sw;
    }
    // row loads (independent of t2s; issue before barrier)
    float hA = B[(size_t)node * 192 + lane];        // H3[lane]
    float hB = B[(size_t)node * 192 + 64 + lane];   // T1[lane]
    __syncthreads();
    float acc = 0.f;
    if (kh == 0) {
      // K 0..63 = H3, K 64..95 = T1[0:32)
#pragma unroll
      for (int k = 0; k < 64; k++) acc = fmaf(rlane(hA, k), wr[k], acc);
#pragma unroll
      for (int k = 64; k < 96; k++) acc = fmaf(rlane(hB, k - 64), wr[k], acc);
    } else {
      float t2v = t2s[lane] - hA;  // T2[lane] = -2*dn*S[lane] - H3[lane]
      // K 96..127 = T1[32:64), K 128..191 = T2
#pragma unroll
      for (int k = 0; k < 32; k++) acc = fmaf(rlane(hB, 32 + k), wr[k], acc);
#pragma unroll
      for (int k = 32; k < 96; k++) acc = fmaf(rlane(t2v, k - 32), wr[k], acc);
      pacc[col] = acc;
    }
    __syncthreads();
    if (kh == 0) {
      float tot = acc + pacc[col] + bb;
      ph4[col] = fmaxf(tot, 0.f);  // H4[node][col], register->LDS only
    }
    __syncthreads();
    // epilogue: ABC5[node][j] = sum_k ph4[k] * wc5[k][j], 4-way k-split
    if (kseg < 4) {
      const float* wrow = &wcs[(32 * kseg) * 60 + j60];
      float part = 0.f;
#pragma unroll
      for (int kk = 0; kk < 32; kk++)
        part = fmaf(ph4[32 * kseg + kk], wrow[kk * 60], part);
      pabc[kseg][j60] = part;
    }
    __syncthreads();
    if (t < 60)
      ABC5[(size_t)node * 60 + t] =
          pabc[0][t] + pabc[1][t] + pabc[2][t] + pabc[3][t];
    __syncthreads();  // WAR: next iteration overwrites t2s/pacc/ph4/pabc
  }
}

// ---------------- kernels (13-dispatch chain; no cooperative launch) --------
// Learnings: grid.sync ~100us -> plain launches. R0-R8: L1 packed dispatch
// invariant 46-57us across SIX GEMM variants -> R0 config is the optimum,
// frozen verbatim (suspected floor = count-branch atomics). Chain is
// per-dispatch-floor dominated (~17us avg) -> fuse row-local stages:
// F2/F3 (R5), F4 (R7), and now L14 absorbed into F4 (R9).

// L0: zero deg/cnt + both weight concats
__global__ __launch_bounds__(NT) void k_zero_wcat(MegaParams p) {
  int tid = blockIdx.x * NT + threadIdx.x;
  int TT = gridDim.x * NT;
  for (int i = tid; i < 2 * NN; i += TT) p.deg[i] = 0;  // deg+cnt contiguous
  for (int i = tid; i < WC1_TOTAL; i += TT) wcat_one(p.W1, p.wc1, i, 782, 16, 16);
  for (int i = tid; i < WC5_TOTAL; i += TT) wcat_one(p.W5, p.wc5, i, 128, 19, 20);
}

// L1: degree count + bucket insert (blocks 0..624) PACKED with
//     L1-GEMM k-split partials (blocks 625..1104) — round-0 proven config.
__global__ __launch_bounds__(NT) void k_count_gemm1(MegaParams p) {
  __shared__ float Ws[72 * 48];  // 13.8 KB (gemm branch only)
  if (blockIdx.x < CNT_BLKS) {
    int e = blockIdx.x * NT + threadIdx.x;  // 0..159999 exactly
    int s = p.src[e], d = p.dst[e];
    atomicAdd(&p.deg[s], 1);
    int slot = atomicAdd(&p.cnt[d], 1);
    if (slot < CAP) p.bsrc[(d << 7) + slot] = s;
  } else {
    gemm_stage<48, false, false>(p.x, 782, p.wc1, 48, p.P, 0, nullptr, 0,
                                 NN, 782, 48, L1_KCHUNK, L1_SPLITS,
                                 blockIdx.x - CNT_BLKS, 1 << 30, Ws);
  }
}

// L2: dinv + reduce ABC1
__global__ __launch_bounds__(NT) void k_reduce_dinv(MegaParams p) {
  int tid = blockIdx.x * NT + threadIdx.x;
  int TT = gridDim.x * NT;
  for (int i = tid; i < NN; i += TT) {
    int d = p.deg[i];
    p.dinv[i] = d > 0 ? 1.0f / sqrtf((float)d) : 0.0f;
  }
  for (int i = tid; i < NN * 48; i += TT) {
    float s = 0.f;
#pragma unroll
    for (int z = 0; z < L1_SPLITS; z++) s += p.P[(size_t)z * (NN * 48) + i];
    p.ABC1[i] = s;
  }
}

// SpMM launcher kernel
__global__ __launch_bounds__(NT) void k_spmm(
    const int* cnt, const int* bsrc, const float* dinv,
    const float* X, int ldx, float* Y, int ldy,
    const float* add, int lda, const float* bias,
    float alpha, float beta, int C_log2, int Fstore, int relu, int do_softmax) {
  spmm_stage(cnt, bsrc, dinv, X, ldx, Y, ldy, add, lda, bias,
             alpha, beta, C_log2, Fstore, relu, do_softmax);
}

// ---------------- host ----------------

extern "C" void kernel_launch(void* const* d_in, const int* in_sizes, int n_in,
                              void* d_out, int out_size, void* d_ws, size_t ws_size,
                              hipStream_t stream) {
  (void)in_sizes; (void)n_in; (void)out_size; (void)ws_size;
  char* p = (char*)d_ws;
  auto alloc = [&](size_t bytes) {
    char* r = p;
    p += (bytes + 255) & ~(size_t)255;
    return r;
  };
  int*   i_deg  = (int*)alloc(sizeof(int) * NN * 2);  // deg, cnt contiguous
  int*   i_bsrc = (int*)alloc(sizeof(int) * NN * CAP);
  float* f_dinv = (float*)alloc(sizeof(float) * NN);
  float* wc1    = (float*)alloc(sizeof(float) * WC1_TOTAL);
  float* wc5    = (float*)alloc(sizeof(float) * WC5_TOTAL);
  float* R1     = (float*)alloc(sizeof(float) * NN * 96);   // ABC1(48)->B3(96)->ABC5(60)
  float* R2     = (float*)alloc(sizeof(float) * NN * 192);  // E1(16)->B4(192)->E5(32)
  float* R3     = (float*)alloc(sizeof(float) * NN * 128);  // B2(48)
  float* P      = (float*)alloc(sizeof(float) * NN * 48 * L1_SPLITS);

  MegaParams mp;
  mp.x   = (const float*)d_in[0];
  const int* ei = (const int*)d_in[1];
  mp.src = ei;
  mp.dst = ei + NE;
  mp.W1 = (const float*)d_in[2];  mp.b1 = (const float*)d_in[3];
  mp.W2 = (const float*)d_in[4];  mp.b2 = (const float*)d_in[5];
  mp.W3 = (const float*)d_in[6];  mp.b3 = (const float*)d_in[7];
  mp.W4 = (const float*)d_in[8];  mp.b4 = (const float*)d_in[9];
  mp.W5 = (const float*)d_in[10]; mp.b5 = (const float*)d_in[11];
  mp.deg = i_deg; mp.cnt = i_deg + NN; mp.bsrc = i_bsrc;
  mp.dinv = f_dinv; mp.wc1 = wc1; mp.wc5 = wc5;
  mp.ABC1 = R1; mp.B3 = R1; mp.ABC5 = R1;
  mp.E1 = R2;   mp.B4 = R2; mp.E5 = R2;
  mp.B2 = R3;   mp.H4 = R3;
  mp.P = P;
  mp.out = (float*)d_out;

  // L0: zero + wcat
  k_zero_wcat<<<160, NT, 0, stream>>>(mp);
  // L1: count (625 blocks) + L1-GEMM partials (480 tiles) — round-0 config
  k_count_gemm1<<<CNT_BLKS + 480, NT, 0, stream>>>(mp);
  // L2: dinv + reduce ABC1
  k_reduce_dinv<<<(NN * 48 + NT - 1) / NT, NT, 0, stream>>>(mp);
  // L3: E1 = 2*L(C) + B
  k_spmm<<<2500, NT, 0, stream>>>(mp.cnt, mp.bsrc, mp.dinv, mp.ABC1 + 32, 48,
                                  mp.E1, 16, mp.ABC1 + 16, 48, nullptr,
                                  2.f, 1.f, 2, 16, 0, 0);
  // L4: H1 = relu(L(E1) + A + b1) -> B2 slot0 (ld48)
  k_spmm<<<2500, NT, 0, stream>>>(mp.cnt, mp.bsrc, mp.dinv, mp.E1, 16,
                                  mp.B2, 48, mp.ABC1, 48, mp.b1,
                                  1.f, 1.f, 2, 16, 1, 0);
  // L5: layer-2 T1 -> B2+16 (ld48)
  k_spmm<<<2500, NT, 0, stream>>>(mp.cnt, mp.bsrc, mp.dinv, mp.B2, 48,
                                  mp.B2 + 16, 48, nullptr, 0, nullptr,
                                  1.f, 0.f, 2, 16, 0, 0);
  // F2: fused layer-2 T2-spmm + [H|T1|T2]@W2+b2, relu -> B3 slot0 (ld96)
  k_fused_t2gemm<16, 2, 48, 48, 32, 96><<<1250, NT, 0, stream>>>(
      mp.cnt, mp.bsrc, mp.dinv, mp.B2, mp.W2, mp.b2, mp.B3);
  // L8: layer-3 T1 -> B3+32 (ld96)
  k_spmm<<<2500, NT, 0, stream>>>(mp.cnt, mp.bsrc, mp.dinv, mp.B3, 96,
                                  mp.B3 + 32, 96, nullptr, 0, nullptr,
                                  1.f, 0.f, 3, 32, 0, 0);
  // F3: fused layer-3 T2-spmm + [H|T1|T2]@W3+b3, relu -> B4 slot0 (ld192)
  k_fused_t2gemm<32, 3, 96, 96, 64, 192><<<1250, NT, 0, stream>>>(
      mp.cnt, mp.bsrc, mp.dinv, mp.B3, mp.W3, mp.b3, mp.B4);
  // L11: layer-4 T1 -> B4+64 (ld192)
  k_spmm<<<2500, NT, 0, stream>>>(mp.cnt, mp.bsrc, mp.dinv, mp.B4, 192,
                                  mp.B4 + 64, 192, nullptr, 0, nullptr,
                                  1.f, 0.f, 4, 64, 0, 0);
  // F4 v3: layer-4 T2-spmm + [H3|T1|T2]@W4+b4+relu + H4@wc5 -> ABC5 (ld60)
  k_fused_t2gemm4<<<2500, NT, 0, stream>>>(
      mp.cnt, mp.bsrc, mp.dinv, mp.B4, mp.W4, mp.b4, mp.wc5, mp.ABC5);
  // L15: E5 = 2*L(C) + B (Fstore 20; cols >= 20 masked)
  k_spmm<<<2500, NT, 0, stream>>>(mp.cnt, mp.bsrc, mp.dinv, mp.ABC5 + 40, 60,
                                  mp.E5, 32, mp.ABC5 + 20, 60, nullptr,
                                  2.f, 1.f, 3, 20, 0, 0);
  // L16: out = softmax(L(E5) + A + b5) (ld19)
  k_spmm<<<2500, NT, 0, stream>>>(mp.cnt, mp.bsrc, mp.dinv, mp.E5, 32,
                                  mp.out, 19, mp.ABC5, 60, mp.b5,
                                  1.f, 1.f, 3, 19, 0, 1);
}

// Round 10
// 254.888 us; speedup vs baseline: 1.0861x; 1.0583x over previous
//
#include <hip/hip_runtime.h>
#include <math.h>

#define NN 10000
#define NE 160000
#define CAP 128     // bucket capacity; P(in-deg >= 128 | Poisson(16)) ~ 1e-60
#define NT 256
#define WC1_TOTAL (782 * 48)
#define WC5_TOTAL (128 * 60)
#define L1_SPLITS 12
#define L1_KCHUNK 66   // even (float2 path); 12*66 >= 782
#define CNT_BLKS 625   // 625*256 == NE exactly

struct MegaParams {
  const float* x;
  const int* src;
  const int* dst;
  const float* W1; const float* b1;
  const float* W2; const float* b2;
  const float* W3; const float* b3;
  const float* W4; const float* b4;
  const float* W5; const float* b5;
  int* deg; int* cnt; int* bsrc;
  float* dinv; float* wc1; float* wc5;
  float* ABC1; float* E1; float* B2; float* B3; float* B4;
  float* H4; float* ABC5; float* E5; float* P;
  float* out;
};

// ---- weight concat: Wc [Fin][3*Fp]: [W0-W2 | W1 | W2], pad cols zero ----
__device__ __forceinline__ void wcat_one(const float* __restrict__ W,
                                         float* __restrict__ Wc,
                                         int i, int Fin, int F, int Fp) {
  int w3 = 3 * Fp;
  int row = i / w3;
  int c = i - row * w3;
  int sec = c / Fp;
  int f = c - sec * Fp;
  float v = 0.0f;
  if (f < F) {
    if (sec == 0)      v = W[row * F + f] - W[2 * Fin * F + row * F + f];
    else if (sec == 1) v = W[Fin * F + row * F + f];
    else               v = W[2 * Fin * F + row * F + f];
  }
  Wc[i] = v;
}

// ---- GEMM stage (register-X prefetch, LDS-W broadcast, RT=1) ----
// VERBATIM round-0 body. FROZEN: six L1-GEMM rewrites (R1-R8) all measured
// 46-57us; this config is the optimum. F4-style fusions of L12/L13/L14
// (R6/R7/R9) all measured WORSE than this plain subchain — do not re-fuse.
struct Row8 { float4 lo, hi; };

template <bool AL16>
__device__ __forceinline__ Row8 ld_row8(const float* __restrict__ X, int ldx,
                                        int gr, int M, int kc, int kend) {
  Row8 r;
  r.lo = make_float4(0.f, 0.f, 0.f, 0.f);
  r.hi = make_float4(0.f, 0.f, 0.f, 0.f);
  if (gr < M && kc < kend) {
    const float* xp = X + (size_t)gr * ldx + kc;
    if (kc + 8 <= kend) {
      if (AL16) {
        r.lo = ((const float4*)xp)[0];
        r.hi = ((const float4*)xp)[1];
      } else {  // rows 8B-aligned only (ldx=782, kc even)
        float2 a = *(const float2*)xp;
        float2 b = *(const float2*)(xp + 2);
        float2 c = *(const float2*)(xp + 4);
        float2 d = *(const float2*)(xp + 6);
        r.lo = make_float4(a.x, a.y, b.x, b.y);
        r.hi = make_float4(c.x, c.y, d.x, d.y);
      }
    } else {
      int rem = kend - kc;  // 1..7
      r.lo.x = xp[0];
      if (rem > 1) r.lo.y = xp[1];
      if (rem > 2) r.lo.z = xp[2];
      if (rem > 3) r.lo.w = xp[3];
      if (rem > 4) r.hi.x = xp[4];
      if (rem > 5) r.hi.y = xp[5];
      if (rem > 6) r.hi.z = xp[6];
    }
  }
  return r;
}

__device__ __forceinline__ float comp8(const Row8& r, int k) {  // k compile-time
  switch (k) {
    case 0: return r.lo.x; case 1: return r.lo.y;
    case 2: return r.lo.z; case 3: return r.lo.w;
    case 4: return r.hi.x; case 5: return r.hi.y;
    case 6: return r.hi.z; default: return r.hi.w;
  }
}

// readlane broadcast: reg value from lane i -> scalar operand (no LDS).
__device__ __forceinline__ float rlane(float v, int i) {
  return __int_as_float(__builtin_amdgcn_readlane(__float_as_int(v), i));
}

// tiles over (row-tile 256) x (col-tile TN) x (k-split), iterated from tile0
// by tstride. DIRECT: fused bias/relu to Y(ldy); else partials P[tz][M*Nd].
template <int TN, bool AL16, bool DIRECT>
__device__ void gemm_stage(const float* __restrict__ X, int ldx,
                           const float* __restrict__ W, int ldw,
                           float* __restrict__ Y, int ldy,
                           const float* __restrict__ bias, int relu,
                           int M, int Kd, int Nd, int kchunk, int nk,
                           int tile0, int tstride, float* Ws) {
  int ntR = (M + NT - 1) / NT;
  int ntC = Nd / TN;  // exact for all uses
  int ntRC = ntR * ntC;
  int ntiles = ntRC * nk;
  constexpr int W4 = TN / 4;
  for (int tile = tile0; tile < ntiles; tile += tstride) {
    int tz = tile / ntRC;
    int rm = tile - tz * ntRC;
    int tc = rm / ntR;
    int tr = rm - tc * ntR;
    int row0 = tr * NT;
    int col0 = tc * TN;
    int k0 = tz * kchunk;
    int kend = k0 + kchunk;
    if (kend > Kd) kend = Kd;
    int k8 = ((kend - k0) + 7) & ~7;
    __syncthreads();  // protect Ws from previous tile's readers
    for (int idx = threadIdx.x; idx < k8 * W4; idx += NT) {
      int wk = idx / W4;
      int wc = (idx - wk * W4) * 4;
      float4 wv = make_float4(0.f, 0.f, 0.f, 0.f);
      if (k0 + wk < kend)
        wv = *(const float4*)(W + (size_t)(k0 + wk) * ldw + col0 + wc);
      *(float4*)(Ws + wk * TN + wc) = wv;
    }
    __syncthreads();
    float acc[TN];
#pragma unroll
    for (int c = 0; c < TN; c++) acc[c] = 0.f;
    int r = row0 + threadIdx.x;
    int nch = k8 >> 3;
    Row8 cur = ld_row8<AL16>(X, ldx, r, M, k0, kend);
    for (int ci = 0; ci < nch; ci++) {
      Row8 nxt = cur;
      if (ci + 1 < nch) nxt = ld_row8<AL16>(X, ldx, r, M, k0 + (ci + 1) * 8, kend);
      int kb = ci << 3;
#pragma unroll
      for (int k = 0; k < 8; k++) {
        float x0 = comp8(cur, k);
        const float* wr = Ws + (kb + k) * TN;
#pragma unroll
        for (int c = 0; c < TN; c += 4) {
          float4 wv = *(const float4*)(wr + c);  // wave-uniform -> LDS broadcast
          acc[c + 0] += x0 * wv.x; acc[c + 1] += x0 * wv.y;
          acc[c + 2] += x0 * wv.z; acc[c + 3] += x0 * wv.w;
        }
      }
      cur = nxt;
    }
    if (r < M) {
      if (DIRECT) {
        float* yr = Y + (size_t)r * ldy + col0;
#pragma unroll
        for (int c = 0; c < TN; c += 4) {
          float4 v;
          v.x = acc[c + 0] + (bias ? bias[col0 + c + 0] : 0.f);
          v.y = acc[c + 1] + (bias ? bias[col0 + c + 1] : 0.f);
          v.z = acc[c + 2] + (bias ? bias[col0 + c + 2] : 0.f);
          v.w = acc[c + 3] + (bias ? bias[col0 + c + 3] : 0.f);
          if (relu) {
            v.x = fmaxf(v.x, 0.f); v.y = fmaxf(v.y, 0.f);
            v.z = fmaxf(v.z, 0.f); v.w = fmaxf(v.w, 0.f);
          }
          *(float4*)(yr + c) = v;
        }
      } else {
        float* pr = Y + ((size_t)tz * M + r) * Nd + col0;
#pragma unroll
        for (int c = 0; c < TN; c += 4)
          *(float4*)(pr + c) = make_float4(acc[c], acc[c + 1], acc[c + 2], acc[c + 3]);
      }
    }
  }
}

// ---- SpMM stage: wave-per-node grid-stride; S = sum dinv[src]*x;
//      u = -alpha*dinv[node]*S + beta*add + bias (+relu | softmax). ----
__device__ void spmm_stage(const int* __restrict__ cnt,
                           const int* __restrict__ bsrc,
                           const float* __restrict__ dinv,
                           const float* __restrict__ X, int ldx,
                           float* __restrict__ Y, int ldy,
                           const float* __restrict__ add, int lda,
                           const float* __restrict__ bias,
                           float alpha, float beta,
                           int C_log2, int Fstore, int relu, int do_softmax) {
  int wv = threadIdx.x >> 6;
  int lane = threadIdx.x & 63;
  int C = 1 << C_log2;
  int chunk = lane & (C - 1);
  int eslot = lane >> C_log2;
  int Epar = 64 >> C_log2;
  for (int node = blockIdx.x * 4 + wv; node < NN; node += gridDim.x * 4) {
    int cn = cnt[node]; if (cn > CAP) cn = CAP;
    float dn = dinv[node];
    int j0 = node << 7;
    int j1 = j0 + cn;
    float sx = 0.f, sy = 0.f, sz = 0.f, sw = 0.f;
    for (int j = j0 + eslot; j < j1; j += Epar) {
      int sn = bsrc[j];
      float w = dinv[sn];  // 40 KB table, cache-hot
      float4 xv = *(const float4*)(X + (size_t)sn * ldx + (chunk << 2));
      sx += w * xv.x; sy += w * xv.y; sz += w * xv.z; sw += w * xv.w;
    }
    for (int st = C; st < 64; st <<= 1) {
      sx += __shfl_xor(sx, st);
      sy += __shfl_xor(sy, st);
      sz += __shfl_xor(sz, st);
      sw += __shfl_xor(sw, st);
    }
    if (eslot == 0) {
      float am = -alpha * dn;
      int f0 = chunk << 2;
      float4 u = make_float4(am * sx, am * sy, am * sz, am * sw);
      if (add) {
        float4 av = *(const float4*)(add + (size_t)node * lda + f0);
        u.x += beta * av.x; u.y += beta * av.y; u.z += beta * av.z; u.w += beta * av.w;
      }
      if (bias) {
        if (f0 + 0 < Fstore) u.x += bias[f0 + 0];
        if (f0 + 1 < Fstore) u.y += bias[f0 + 1];
        if (f0 + 2 < Fstore) u.z += bias[f0 + 2];
        if (f0 + 3 < Fstore) u.w += bias[f0 + 3];
      }
      if (!do_softmax) {
        if (relu) {
          u.x = fmaxf(u.x, 0.f); u.y = fmaxf(u.y, 0.f);
          u.z = fmaxf(u.z, 0.f); u.w = fmaxf(u.w, 0.f);
        }
        if (f0 + 4 <= Fstore) {
          *(float4*)(Y + (size_t)node * ldy + f0) = u;
        } else {
          float vv[4] = {u.x, u.y, u.z, u.w};
#pragma unroll
          for (int c = 0; c < 4; c++)
            if (f0 + c < Fstore) Y[(size_t)node * ldy + f0 + c] = vv[c];
        }
      } else {
        float v[4] = {u.x, u.y, u.z, u.w};
        float mx = -INFINITY;
#pragma unroll
        for (int c = 0; c < 4; c++)
          if (f0 + c < Fstore) mx = fmaxf(mx, v[c]);
        mx = fmaxf(mx, __shfl_xor(mx, 1));
        mx = fmaxf(mx, __shfl_xor(mx, 2));
        mx = fmaxf(mx, __shfl_xor(mx, 4));
        float e[4];
        float s = 0.f;
#pragma unroll
        for (int c = 0; c < 4; c++) {
          e[c] = (f0 + c < Fstore) ? __expf(v[c] - mx) : 0.f;
          s += e[c];
        }
        s += __shfl_xor(s, 1);
        s += __shfl_xor(s, 2);
        s += __shfl_xor(s, 4);
        float inv = 1.f / s;
#pragma unroll
        for (int c = 0; c < 4; c++) {
          int f = f0 + c;
          if (f < Fstore) Y[(size_t)node * ldy + f] = e[c] * inv;
        }
      }
    }
  }
}

// ---- FUSED T2-spmm + row-GEMM (+bias+relu), layers 2/3 (R5-verified) -----
template <int F, int C_log2, int LD, int KK, int FOUT, int LDO>
__global__ __launch_bounds__(NT) void k_fused_t2gemm(
    const int* __restrict__ cnt, const int* __restrict__ bsrc,
    const float* __restrict__ dinv, const float* __restrict__ B,
    const float* __restrict__ W, const float* __restrict__ bias,
    float* __restrict__ Y) {
  int wv = threadIdx.x >> 6;
  int lane = threadIdx.x & 63;
  constexpr int C = 1 << C_log2;
  int chunk = lane & (C - 1);
  int eslot = lane >> C_log2;
  constexpr int Epar = 64 >> C_log2;
  int col = lane % FOUT;  // FOUT=32: halves duplicate; FOUT=64: all lanes
  float wr[KK];
#pragma unroll
  for (int k = 0; k < KK; k++) wr[k] = W[k * FOUT + col];
  float bb = bias[col];
  for (int node = blockIdx.x * 4 + wv; node < NN; node += gridDim.x * 4) {
    int cn = cnt[node]; if (cn > CAP) cn = CAP;
    float dn = dinv[node];
    int j0 = node << 7, j1 = j0 + cn;
    float sx = 0.f, sy = 0.f, sz = 0.f, sw = 0.f;
    for (int j = j0 + eslot; j < j1; j += Epar) {
      int sn = bsrc[j];
      float w = dinv[sn];
      float4 xv = *(const float4*)(B + (size_t)sn * LD + F + (chunk << 2));
      sx += w * xv.x; sy += w * xv.y; sz += w * xv.z; sw += w * xv.w;
    }
#pragma unroll
    for (int st = C; st < 64; st <<= 1) {  // full butterfly: ALL lanes get S
      sx += __shfl_xor(sx, st);
      sy += __shfl_xor(sy, st);
      sz += __shfl_xor(sz, st);
      sw += __shfl_xor(sw, st);
    }
    int ridx = (lane < 2 * F) ? lane : (lane - 2 * F);
    float rv0 = B[(size_t)node * LD + ridx];  // l>=2F lanes hold H[l-2F]
    int f = (KK == 48) ? (lane - 2 * F) : lane;
    int cc = (f >> 2) & (C - 1);
    float a0 = __shfl(sx, cc), a1 = __shfl(sy, cc);
    float a2 = __shfl(sz, cc), a3 = __shfl(sw, cc);
    int comp = f & 3;
    float Ssel = (comp == 0) ? a0 : (comp == 1) ? a1 : (comp == 2) ? a2 : a3;
    float t2v = fmaf(-2.f * dn, Ssel, -rv0);
    float acc = bb;
    if (KK == 48) {
      float rv = (lane < 2 * F) ? rv0 : t2v;
#pragma unroll
      for (int k = 0; k < 48; k++) acc = fmaf(rlane(rv, k), wr[k], acc);
    } else {
#pragma unroll
      for (int k = 0; k < 64; k++) acc = fmaf(rlane(rv0, k), wr[k], acc);
#pragma unroll
      for (int k = 64; k < 96; k++) acc = fmaf(rlane(t2v, k - 64), wr[k], acc);
    }
    acc = fmaxf(acc, 0.f);
    if (lane < FOUT) Y[(size_t)node * LDO + col] = acc;
  }
}

// ---------------- kernels (15-dispatch chain; no cooperative launch) --------
// Learnings: grid.sync ~100us -> plain launches. R0-R9 ledger:
//  - L1 packed count+gemm1: R0 config optimal (46-48us), frozen.
//  - F2/F3 fusions: verified win (R4->R5, -14us).
//  - F4 fusions of L12/L13(/L14): ALL variants measured ~13us WORSE than the
//    plain L11/L12/L13+L14 subchain (reg-spill + serial readlane chains +
//    barriers). Reverted permanently; this round combines the two best
//    measured halves: verbatim-R0 L1 + R5's non-L1 chain.

// L0: zero deg/cnt + both weight concats
__global__ __launch_bounds__(NT) void k_zero_wcat(MegaParams p) {
  int tid = blockIdx.x * NT + threadIdx.x;
  int TT = gridDim.x * NT;
  for (int i = tid; i < 2 * NN; i += TT) p.deg[i] = 0;  // deg+cnt contiguous
  for (int i = tid; i < WC1_TOTAL; i += TT) wcat_one(p.W1, p.wc1, i, 782, 16, 16);
  for (int i = tid; i < WC5_TOTAL; i += TT) wcat_one(p.W5, p.wc5, i, 128, 19, 20);
}

// L1: degree count + bucket insert (blocks 0..624) PACKED with
//     L1-GEMM k-split partials (blocks 625..1104) — round-0 proven config.
__global__ __launch_bounds__(NT) void k_count_gemm1(MegaParams p) {
  __shared__ float Ws[72 * 48];  // 13.8 KB (gemm branch only)
  if (blockIdx.x < CNT_BLKS) {
    int e = blockIdx.x * NT + threadIdx.x;  // 0..159999 exactly
    int s = p.src[e], d = p.dst[e];
    atomicAdd(&p.deg[s], 1);
    int slot = atomicAdd(&p.cnt[d], 1);
    if (slot < CAP) p.bsrc[(d << 7) + slot] = s;
  } else {
    gemm_stage<48, false, false>(p.x, 782, p.wc1, 48, p.P, 0, nullptr, 0,
                                 NN, 782, 48, L1_KCHUNK, L1_SPLITS,
                                 blockIdx.x - CNT_BLKS, 1 << 30, Ws);
  }
}

// L2: dinv + reduce ABC1
__global__ __launch_bounds__(NT) void k_reduce_dinv(MegaParams p) {
  int tid = blockIdx.x * NT + threadIdx.x;
  int TT = gridDim.x * NT;
  for (int i = tid; i < NN; i += TT) {
    int d = p.deg[i];
    p.dinv[i] = d > 0 ? 1.0f / sqrtf((float)d) : 0.0f;
  }
  for (int i = tid; i < NN * 48; i += TT) {
    float s = 0.f;
#pragma unroll
    for (int z = 0; z < L1_SPLITS; z++) s += p.P[(size_t)z * (NN * 48) + i];
    p.ABC1[i] = s;
  }
}

// SpMM launcher kernel
__global__ __launch_bounds__(NT) void k_spmm(
    const int* cnt, const int* bsrc, const float* dinv,
    const float* X, int ldx, float* Y, int ldy,
    const float* add, int lda, const float* bias,
    float alpha, float beta, int C_log2, int Fstore, int relu, int do_softmax) {
  spmm_stage(cnt, bsrc, dinv, X, ldx, Y, ldy, add, lda, bias,
             alpha, beta, C_log2, Fstore, relu, do_softmax);
}

// Direct GEMM launcher kernels (full-K, fused bias/relu) — R0/R5-verbatim
__global__ __launch_bounds__(NT, 2) void k_gemm16(
    const float* X, int ldx, const float* W, int ldw, float* Y, int ldy,
    const float* bias, int relu, int Kd, int Nd) {
  __shared__ float Ws[192 * 16];
  gemm_stage<16, true, true>(X, ldx, W, ldw, Y, ldy, bias, relu,
                             NN, Kd, Nd, Kd, 1, blockIdx.x, gridDim.x, Ws);
}
__global__ __launch_bounds__(NT, 2) void k_gemm20(
    const float* X, int ldx, const float* W, int ldw, float* Y, int ldy,
    const float* bias, int relu, int Kd, int Nd) {
  __shared__ float Ws[128 * 20];
  gemm_stage<20, true, true>(X, ldx, W, ldw, Y, ldy, bias, relu,
                             NN, Kd, Nd, Kd, 1, blockIdx.x, gridDim.x, Ws);
}

// ---------------- host ----------------

extern "C" void kernel_launch(void* const* d_in, const int* in_sizes, int n_in,
                              void* d_out, int out_size, void* d_ws, size_t ws_size,
                              hipStream_t stream) {
  (void)in_sizes; (void)n_in; (void)out_size; (void)ws_size;
  char* p = (char*)d_ws;
  auto alloc = [&](size_t bytes) {
    char* r = p;
    p += (bytes + 255) & ~(size_t)255;
    return r;
  };
  int*   i_deg  = (int*)alloc(sizeof(int) * NN * 2);  // deg, cnt contiguous
  int*   i_bsrc = (int*)alloc(sizeof(int) * NN * CAP);
  float* f_dinv = (float*)alloc(sizeof(float) * NN);
  float* wc1    = (float*)alloc(sizeof(float) * WC1_TOTAL);
  float* wc5    = (float*)alloc(sizeof(float) * WC5_TOTAL);
  float* R1     = (float*)alloc(sizeof(float) * NN * 96);   // ABC1(48)->B3(96)->ABC5(60)
  float* R2     = (float*)alloc(sizeof(float) * NN * 192);  // E1(16)->B4(192)->E5(32)
  float* R3     = (float*)alloc(sizeof(float) * NN * 128);  // B2(48)->H4(128)
  float* P      = (float*)alloc(sizeof(float) * NN * 48 * L1_SPLITS);

  MegaParams mp;
  mp.x   = (const float*)d_in[0];
  const int* ei = (const int*)d_in[1];
  mp.src = ei;
  mp.dst = ei + NE;
  mp.W1 = (const float*)d_in[2];  mp.b1 = (const float*)d_in[3];
  mp.W2 = (const float*)d_in[4];  mp.b2 = (const float*)d_in[5];
  mp.W3 = (const float*)d_in[6];  mp.b3 = (const float*)d_in[7];
  mp.W4 = (const float*)d_in[8];  mp.b4 = (const float*)d_in[9];
  mp.W5 = (const float*)d_in[10]; mp.b5 = (const float*)d_in[11];
  mp.deg = i_deg; mp.cnt = i_deg + NN; mp.bsrc = i_bsrc;
  mp.dinv = f_dinv; mp.wc1 = wc1; mp.wc5 = wc5;
  mp.ABC1 = R1; mp.B3 = R1; mp.ABC5 = R1;
  mp.E1 = R2;   mp.B4 = R2; mp.E5 = R2;
  mp.B2 = R3;   mp.H4 = R3;
  mp.P = P;
  mp.out = (float*)d_out;

  // L0: zero + wcat
  k_zero_wcat<<<160, NT, 0, stream>>>(mp);
  // L1: count (625 blocks) + L1-GEMM partials (480 tiles) — round-0 config
  k_count_gemm1<<<CNT_BLKS + 480, NT, 0, stream>>>(mp);
  // L2: dinv + reduce ABC1
  k_reduce_dinv<<<(NN * 48 + NT - 1) / NT, NT, 0, stream>>>(mp);
  // L3: E1 = 2*L(C) + B
  k_spmm<<<2500, NT, 0, stream>>>(mp.cnt, mp.bsrc, mp.dinv, mp.ABC1 + 32, 48,
                                  mp.E1, 16, mp.ABC1 + 16, 48, nullptr,
                                  2.f, 1.f, 2, 16, 0, 0);
  // L4: H1 = relu(L(E1) + A + b1) -> B2 slot0 (ld48)
  k_spmm<<<2500, NT, 0, stream>>>(mp.cnt, mp.bsrc, mp.dinv, mp.E1, 16,
                                  mp.B2, 48, mp.ABC1, 48, mp.b1,
                                  1.f, 1.f, 2, 16, 1, 0);
  // L5: layer-2 T1 -> B2+16 (ld48)
  k_spmm<<<2500, NT, 0, stream>>>(mp.cnt, mp.bsrc, mp.dinv, mp.B2, 48,
                                  mp.B2 + 16, 48, nullptr, 0, nullptr,
                                  1.f, 0.f, 2, 16, 0, 0);
  // F2: fused layer-2 T2-spmm + [H|T1|T2]@W2+b2, relu -> B3 slot0 (ld96)
  k_fused_t2gemm<16, 2, 48, 48, 32, 96><<<1250, NT, 0, stream>>>(
      mp.cnt, mp.bsrc, mp.dinv, mp.B2, mp.W2, mp.b2, mp.B3);
  // L8: layer-3 T1 -> B3+32 (ld96)
  k_spmm<<<2500, NT, 0, stream>>>(mp.cnt, mp.bsrc, mp.dinv, mp.B3, 96,
                                  mp.B3 + 32, 96, nullptr, 0, nullptr,
                                  1.f, 0.f, 3, 32, 0, 0);
  // F3: fused layer-3 T2-spmm + [H|T1|T2]@W3+b3, relu -> B4 slot0 (ld192)
  k_fused_t2gemm<32, 3, 96, 96, 64, 192><<<1250, NT, 0, stream>>>(
      mp.cnt, mp.bsrc, mp.dinv, mp.B3, mp.W3, mp.b3, mp.B4);
  // L11/L12: layer-4 T1, T2 in B4 (ld192)
  k_spmm<<<2500, NT, 0, stream>>>(mp.cnt, mp.bsrc, mp.dinv, mp.B4, 192,
                                  mp.B4 + 64, 192, nullptr, 0, nullptr,
                                  1.f, 0.f, 4, 64, 0, 0);
  k_spmm<<<2500, NT, 0, stream>>>(mp.cnt, mp.bsrc, mp.dinv, mp.B4 + 64, 192,
                                  mp.B4 + 128, 192, mp.B4, 192, nullptr,
                                  2.f, -1.f, 4, 64, 0, 0);
  // L13: H4 = relu(B4 @ W4 + b4) (ld128), direct full-K (RT=1, 320 blocks)
  k_gemm16<<<320, NT, 0, stream>>>(mp.B4, 192, mp.W4, 128, mp.H4, 128, mp.b4, 1,
                                   192, 128);
  // L14: ABC5 = H4 @ wc5 (ld60)
  k_gemm20<<<120, NT, 0, stream>>>(mp.H4, 128, mp.wc5, 60, mp.ABC5, 60, nullptr, 0,
                                   128, 60);
  // L15: E5 = 2*L(C) + B (Fstore 20; cols >= 20 masked)
  k_spmm<<<2500, NT, 0, stream>>>(mp.cnt, mp.bsrc, mp.dinv, mp.ABC5 + 40, 60,
                                  mp.E5, 32, mp.ABC5 + 20, 60, nullptr,
                                  2.f, 1.f, 3, 20, 0, 0);
  // L16: out = softmax(L(E5) + A + b5) (ld19)
  k_spmm<<<2500, NT, 0, stream>>>(mp.cnt, mp.bsrc, mp.dinv, mp.E5, 32,
                                  mp.out, 19, mp.ABC5, 60, mp.b5,
                                  1.f, 1.f, 3, 19, 0, 1);
}